// Round 6
// baseline (585.682 us; speedup 1.0000x reference)
//
#include <hip/hip_runtime.h>
#include <stdint.h>
#include <math.h>

// Problem constants (B=4,S=2048 -> T=8192; H=1024; 2H=2048; E=8; K=2)
#define T_TOK 8192
#define H_DIM 1024
#define H2    2048
#define NE    8

typedef unsigned short u16;
typedef __attribute__((ext_vector_type(8))) short bf16x8;   // 8 bf16 in 4 VGPRs
typedef __attribute__((ext_vector_type(4))) float f32x4;    // MFMA 16x16 C/D
typedef __attribute__((ext_vector_type(4))) unsigned int u32x4;

__device__ __forceinline__ u16 f32_to_bf16(float f) {
  union { float f; unsigned u; } c; c.f = f;
  unsigned u = c.u + 0x7fffu + ((c.u >> 16) & 1u);  // RNE
  return (u16)(u >> 16);
}
__device__ __forceinline__ float bf2f(u16 v) {
  union { unsigned u; float f; } c; c.u = (unsigned)v << 16; return c.f;
}
// pack two f32 -> two RNE bf16 in one u32 (lo in low half)
__device__ __forceinline__ unsigned pk_bf16(float lo, float hi) {
  union { float f; unsigned u; } a, b; a.f = lo; b.f = hi;
  unsigned ua = a.u + 0x7fffu + ((a.u >> 16) & 1u);
  unsigned ub = b.u + 0x7fffu + ((b.u >> 16) & 1u);
  return (ua >> 16) | (ub & 0xffff0000u);
}

// fast gelu (tanh form), |err| vs exact erf-gelu <= ~1e-3 (absmax 1.56e-2
// vs threshold 4.9e-2, stable across rounds)
__device__ __forceinline__ float fast_gelu(float v) {
  float u = v * v;
  float z2 = v * fmaf(u, 0.1029437f, 2.3022078f);
  float e = __builtin_amdgcn_exp2f(z2);
  float r = __builtin_amdgcn_rcpf(1.0f + e);
  return v - v * r;
}

// async global->LDS, 16B per lane. LDS dest is wave-uniform base + lane*16;
// global address is per-lane (exploited for the XOR bank swizzle).
__device__ __forceinline__ void g2l16(const void* g, void* l) {
  __builtin_amdgcn_global_load_lds(
      (const __attribute__((address_space(1))) unsigned*)g,
      (__attribute__((address_space(3))) unsigned*)l, 16, 0, 0);
}

// exclusive prefix of 8 counts, computed per-block
__device__ __forceinline__ int prefix_base(const int* counts, int e) {
  int b = 0;
#pragma unroll
  for (int j = 0; j < NE; j++) b += (j < e) ? counts[j] : 0;
  return b;
}

// ---------------- Prep: router ONLY (R4/R5 accounting: each 100MB weight
// cvt pass costs ~100us at ~1.8TB/s effective -> the cvt pass must not
// exist; weights are now consumed as f32 directly by the GEMMs).
// One wave per token; fp64 logits -> exact ranking vs reference top-k.
__global__ __launch_bounds__(256) void prep_kernel(
    const float* __restrict__ x, const float* __restrict__ rw,
    u16* __restrict__ xb, int* __restrict__ tope, float2* __restrict__ gate2,
    int* __restrict__ counts) {
  int blk = blockIdx.x;
  if (blk == 0 && threadIdx.x < NE) counts[threadIdx.x] = 0;
  int wave = threadIdx.x >> 6;
  int lane = threadIdx.x & 63;
  int t = blk * 4 + wave;
  const float4* x4 = (const float4*)(x + (size_t)t * H_DIM);
  const float4* rw4 = (const float4*)rw;
  u16* xbrow = xb + (size_t)t * H_DIM;

  double acc[NE];
#pragma unroll
  for (int e = 0; e < NE; e++) acc[e] = 0.0;
#pragma unroll
  for (int i = 0; i < 4; i++) {
    int c = lane + 64 * i;
    float4 xv = x4[c];
    ushort4 bv = make_ushort4(f32_to_bf16(xv.x), f32_to_bf16(xv.y),
                              f32_to_bf16(xv.z), f32_to_bf16(xv.w));
    *(ushort4*)(xbrow + c * 4) = bv;
#pragma unroll
    for (int e = 0; e < NE; e++) {
      float4 wv = rw4[e * 256 + c];
      acc[e] += (double)xv.x * wv.x + (double)xv.y * wv.y +
                (double)xv.z * wv.z + (double)xv.w * wv.w;
    }
  }
#pragma unroll
  for (int off = 32; off >= 1; off >>= 1)
#pragma unroll
    for (int e = 0; e < NE; e++) acc[e] += __shfl_xor(acc[e], off, 64);

  if (lane == 0) {
    int e0 = 0; double v0 = acc[0];
#pragma unroll
    for (int e = 1; e < NE; e++) if (acc[e] > v0) { v0 = acc[e]; e0 = e; }
    int e1 = -1; double v1 = -1e300;
#pragma unroll
    for (int e = 0; e < NE; e++) if (e != e0 && acc[e] > v1) { v1 = acc[e]; e1 = e; }
    double ex = exp(v1 - v0);
    tope[t] = e0 | (e1 << 8);
    gate2[t] = make_float2((float)(1.0 / (1.0 + ex)), (float)(ex / (1.0 + ex)));
  }
}

// ---------------- Build expert lists: counting sort over 8 bins.
__global__ __launch_bounds__(256) void build_kernel(
    const int* __restrict__ tope, int* __restrict__ counts,
    int* __restrict__ tok_list, int2* __restrict__ pos2) {
  __shared__ int cts[4][NE];
  __shared__ int gbase[NE];
  int tid = threadIdx.x, lane = tid & 63, w = tid >> 6;
  int t = blockIdx.x * 256 + tid;
  int pk = tope[t];
  int e0 = pk & 0xff, e1 = (pk >> 8) & 0xff;
  unsigned long long lt = ((unsigned long long)1 << lane) - 1;

  int r0 = 0, r1 = 0;
#pragma unroll
  for (int e = 0; e < NE; e++) {
    unsigned long long b0 = __ballot(e0 == e);
    unsigned long long b1 = __ballot(e1 == e);
    int n0 = __popcll(b0), n1 = __popcll(b1);
    if (e0 == e) r0 = __popcll(b0 & lt);
    if (e1 == e) r1 = n0 + __popcll(b1 & lt);
    if (lane == 0) cts[w][e] = n0 + n1;
  }
  __syncthreads();
  if (tid < NE) {
    int bt = cts[0][tid] + cts[1][tid] + cts[2][tid] + cts[3][tid];
    gbase[tid] = atomicAdd(&counts[tid], bt);
  }
  __syncthreads();
  int off0 = gbase[e0] + r0;
  int off1 = gbase[e1] + r1;
#pragma unroll
  for (int wp = 0; wp < 4; wp++) {
    if (wp < w) { off0 += cts[wp][e0]; off1 += cts[wp][e1]; }
  }
  tok_list[e0 * T_TOK + off0] = t;
  tok_list[e1 * T_TOK + off1] = t;
  pos2[t] = make_int2(off0, off1);
}

// ---------------- Grouped GEMM, R6: 8-wave 256x256 tile, BK=32, f32 B.
// B is staged DIRECTLY from the f32 weights via g2l16 into an f32 LDS tile
// (no prep conversion pass, no VGPR round-trip -> no R4-style spill) and
// converted to bf16 fragments at ds_read time (short register lifetime,
// ~64 VALU/wave/tile hidden under 1241 cyc of MFMA).
//
// Per-tile compute window = 8 waves x 32 MFMA ~= 1241 cyc/CU >= HBM
// latency (~900) -> the single top-of-tile vmcnt(0) stays ~free (R5's
// failure was a 620-cyc window at 4 waves). R3's proven minimum-sync loop:
//   vmcnt(0); s_barrier        // retires stage(t), issued a full tile ago
//   stage(t+1) -> buf d^1      // 6 g2l16 (WAR-safe: reads of d^1 retired
//                              //  before every wave passed this barrier)
//   8 ds_read_b128 (A bf16) + 8 (B f32); cvt B; setprio(1); 32 MFMA
//
// Swizzle (both-sides-or-neither, proven 0-conflict family from R3):
//   A (64B rows, 4 chunks):  phys = logical ^ (row&3)
//   B (128B rows, 8 chunks): phys = logical ^ (row&7)
// staged via pre-swizzled GLOBAL source + linear LDS dest (g2l16 rule).
// XCD pinning: e = blockIdx&7 (bijective, grid %8==0) -> each expert's
// f32 weight panel lives in one XCD's L2 (R3: FETCH 164->57MB).
// LDS 96 KB -> 1 block/CU.
template <int NKT, int NT, int OUTN, bool GATHER, bool GELU>
__global__ __launch_bounds__(512, 1) void moe_gemm(
    const u16* __restrict__ A, const float* __restrict__ Wf,
    u16* __restrict__ O, const int* __restrict__ tok_list,
    const int* __restrict__ counts) {
  const int K = NKT * 32;
  int e = blockIdx.x & 7;
  int rem = blockIdx.x >> 3;
  int mt = rem / NT, nt = rem % NT;
  int cnt = counts[e];
  int m0 = mt * 256;
  if (m0 >= cnt) return;
  int base = prefix_base(counts, e);

  __shared__ u16 lA[2][8192];    // [dbuf][256 rows][32 bf16] = 32 KB
  __shared__ float lB[2][8192];  // [dbuf][256 rows][32 f32]  = 64 KB

  int tid = threadIdx.x;
  int ln = tid & 63, w = tid >> 6;
  int wr = w >> 2, wc = w & 3;             // 2M x 4N wave grid
  int quad = ln >> 4, l16 = ln & 15;

  // ---- A staging: 1024 16B-units/buf (4 chunks/row), 2 g2l16/thread
  const u16* aptr[2];
#pragma unroll
  for (int c2 = 0; c2 < 2; ++c2) {
    int u = c2 * 512 + tid;
    int row = u >> 2, lg = (u & 3) ^ (row & 3);
    int ar = m0 + row; if (ar > cnt - 1) ar = cnt - 1;
    const u16* ab;
    if (GATHER) ab = A + (size_t)tok_list[e * T_TOK + ar] * K;
    else        ab = A + (size_t)(base + ar) * K;
    aptr[c2] = ab + lg * 8;
  }
  // ---- B staging: 2048 16B-units/buf (8 chunks/row), 4 g2l16/thread
  const float* We = Wf + (size_t)e * OUTN * K;
  const float* bptr[4];
#pragma unroll
  for (int c2 = 0; c2 < 4; ++c2) {
    int u = c2 * 512 + tid;
    int row = u >> 3, lg = (u & 7) ^ (row & 7);
    bptr[c2] = We + (size_t)(nt * 256 + row) * K + lg * 4;
  }

  // ---- read addresses
  int adA[8];                              // u16 index within lA buf
#pragma unroll
  for (int f = 0; f < 8; ++f) {
    int r = wr * 128 + f * 16 + l16;
    adA[f] = r * 32 + ((quad ^ (r & 3)) << 3);
  }
  int adB[4][2];                           // f32 index within lB buf
#pragma unroll
  for (int j = 0; j < 4; ++j) {
    int r = wc * 64 + j * 16 + l16;
#pragma unroll
    for (int s = 0; s < 2; ++s)
      adB[j][s] = r * 32 + ((((quad << 1) | s) ^ (r & 7)) << 2);
  }

  f32x4 acc[8][4];
#pragma unroll
  for (int i = 0; i < 8; i++)
#pragma unroll
    for (int j = 0; j < 4; j++)
#pragma unroll
      for (int r = 0; r < 4; r++) acc[i][j][r] = 0.f;

  // prologue: tile 0 in flight
#pragma unroll
  for (int c2 = 0; c2 < 2; ++c2) g2l16(aptr[c2], &lA[0][(c2 * 512 + tid) * 8]);
#pragma unroll
  for (int c2 = 0; c2 < 4; ++c2) g2l16(bptr[c2], &lB[0][(c2 * 512 + tid) * 4]);

#pragma unroll 1
  for (int t = 0; t < NKT; ++t) {
    int d = t & 1;
    asm volatile("s_waitcnt vmcnt(0)" ::: "memory");
    __builtin_amdgcn_s_barrier();
    __builtin_amdgcn_sched_barrier(0);

    if (t + 1 < NKT) {
#pragma unroll
      for (int c2 = 0; c2 < 2; ++c2)
        g2l16(aptr[c2] + (t + 1) * 32, &lA[d ^ 1][(c2 * 512 + tid) * 8]);
#pragma unroll
      for (int c2 = 0; c2 < 4; ++c2)
        g2l16(bptr[c2] + (t + 1) * 32, &lB[d ^ 1][(c2 * 512 + tid) * 4]);
    }

    // ds_reads: B f32 first (feeds cvt), then A bf16
    bf16x8 af[8];
    float4 b0[4], b1[4];
#pragma unroll
    for (int j = 0; j < 4; ++j) {
      b0[j] = *(const float4*)(&lB[d][0] + adB[j][0]);
      b1[j] = *(const float4*)(&lB[d][0] + adB[j][1]);
    }
#pragma unroll
    for (int f = 0; f < 8; ++f) af[f] = *(const bf16x8*)(&lA[d][0] + adA[f]);
    __builtin_amdgcn_sched_barrier(0);

    // f32 -> bf16 fragment pack (RNE); ~16 VALU pairs, dies before MFMA end
    bf16x8 bf[4];
#pragma unroll
    for (int j = 0; j < 4; ++j) {
      union { bf16x8 h; u32x4 u; } cv;
      cv.u.x = pk_bf16(b0[j].x, b0[j].y);
      cv.u.y = pk_bf16(b0[j].z, b0[j].w);
      cv.u.z = pk_bf16(b1[j].x, b1[j].y);
      cv.u.w = pk_bf16(b1[j].z, b1[j].w);
      bf[j] = cv.h;
    }

    __builtin_amdgcn_s_setprio(1);
#pragma unroll
    for (int mi = 0; mi < 8; ++mi)
#pragma unroll
      for (int ni = 0; ni < 4; ++ni)
        acc[mi][ni] = __builtin_amdgcn_mfma_f32_16x16x32_bf16(
            af[mi], bf[ni], acc[mi][ni], 0, 0, 0);
    __builtin_amdgcn_s_setprio(0);
  }

  // epilogue: C/D layout col=lane&15, row=quad*4+reg
#pragma unroll
  for (int mi = 0; mi < 8; ++mi) {
    int rb = wr * 128 + mi * 16 + quad * 4;
#pragma unroll
    for (int r = 0; r < 4; ++r) {
      int grow = m0 + rb + r;
      if (grow < cnt) {
        size_t o = (size_t)(base + grow) * OUTN + nt * 256 + wc * 64 + l16;
#pragma unroll
        for (int ni = 0; ni < 4; ++ni) {
          float v = acc[mi][ni][r];
          if (GELU) v = fast_gelu(v);
          O[o + ni * 16] = f32_to_bf16(v);
        }
      }
    }
  }
}

// ---------------- Combine: out[t] = g0*y[slot0(t)] + g1*y[slot1(t)]
__global__ __launch_bounds__(256) void combine_kernel(
    const u16* __restrict__ y, const int* __restrict__ tope,
    const float2* __restrict__ gate2, const int2* __restrict__ pos2,
    const int* __restrict__ counts, float* __restrict__ out) {
  int t = blockIdx.x;
  int pk = tope[t];
  int e0 = pk & 0xff, e1 = (pk >> 8) & 0xff;
  float2 g = gate2[t];
  int2 p = pos2[t];
  int hb0 = prefix_base(counts, e0);
  int hb1 = prefix_base(counts, e1);
  size_t s0 = (size_t)(hb0 + p.x) * H_DIM + threadIdx.x * 4;
  size_t s1 = (size_t)(hb1 + p.y) * H_DIM + threadIdx.x * 4;
  ushort4 a = *(const ushort4*)(y + s0);
  ushort4 b = *(const ushort4*)(y + s1);
  float4 o;
  o.x = g.x * bf2f(a.x) + g.y * bf2f(b.x);
  o.y = g.x * bf2f(a.y) + g.y * bf2f(b.y);
  o.z = g.x * bf2f(a.z) + g.y * bf2f(b.z);
  o.w = g.x * bf2f(a.w) + g.y * bf2f(b.w);
  *(float4*)(out + (size_t)t * H_DIM + threadIdx.x * 4) = o;
}

extern "C" void kernel_launch(void* const* d_in, const int* in_sizes, int n_in,
                              void* d_out, int out_size, void* d_ws, size_t ws_size,
                              hipStream_t stream) {
  const float* x  = (const float*)d_in[0];
  const float* rw = (const float*)d_in[1];
  const float* w1 = (const float*)d_in[2];
  const float* w2 = (const float*)d_in[3];
  float* out = (float*)d_out;

  // ws layout (bytes), total ~118 MB (weight-bf16 buffers eliminated)
  char* ws = (char*)d_ws;
  u16* xb       = (u16*)(ws);                        // 16,777,216
  u16* h        = (u16*)(ws + 16777216);             // 67,108,864
  u16* y        = (u16*)(ws + 83886080);             // 33,554,432
  int* tok_list = (int*)(ws + 117440512);            // 262,144
  int* tope     = (int*)(ws + 117702656);            // 32,768
  float2* gate2 = (float2*)(ws + 117735424);         // 65,536
  int2* pos2    = (int2*)(ws + 117800960);           // 65,536
  int* counts   = (int*)(ws + 117866496);            // 32

  prep_kernel<<<T_TOK / 4, 256, 0, stream>>>(x, rw, xb, tope, gate2, counts);
  build_kernel<<<T_TOK / 256, 256, 0, stream>>>(tope, counts, tok_list, pos2);
  // g1: gathered [cnt_e,1024](bf16) @ w1[e](f32, staged+cvt in-kernel) -> gelu -> h
  moe_gemm<32, 8, H2, true, true>
      <<<8 * 32 * 8, 512, 0, stream>>>(xb, w1, h, tok_list, counts);
  // g2: h [cnt_e,2048] @ w2[e](f32) -> y [.,1024]
  moe_gemm<64, 4, H_DIM, false, false>
      <<<8 * 32 * 4, 512, 0, stream>>>(h, w2, y, tok_list, counts);
  combine_kernel<<<T_TOK, 256, 0, stream>>>(y, tope, gate2, pos2, counts, out);
}

// Round 7
// 378.035 us; speedup vs baseline: 1.5493x; 1.5493x over previous
//
#include <hip/hip_runtime.h>
#include <stdint.h>
#include <math.h>

// Problem constants (B=4,S=2048 -> T=8192; H=1024; 2H=2048; E=8; K=2)
#define T_TOK 8192
#define H_DIM 1024
#define H2    2048
#define NE    8

typedef unsigned short u16;
typedef __attribute__((ext_vector_type(8))) short bf16x8;   // 8 bf16 in 4 VGPRs
typedef __attribute__((ext_vector_type(4))) float f32x4;    // MFMA 16x16 C/D

__device__ __forceinline__ u16 f32_to_bf16(float f) {
  union { float f; unsigned u; } c; c.f = f;
  unsigned u = c.u + 0x7fffu + ((c.u >> 16) & 1u);  // RNE
  return (u16)(u >> 16);
}
__device__ __forceinline__ float bf2f(u16 v) {
  union { unsigned u; float f; } c; c.u = (unsigned)v << 16; return c.f;
}

// fast gelu (tanh form), |err| vs exact erf-gelu <= ~1e-3 (absmax 1.56e-2
// vs threshold 4.9e-2, stable across rounds)
__device__ __forceinline__ float fast_gelu(float v) {
  float u = v * v;
  float z2 = v * fmaf(u, 0.1029437f, 2.3022078f);
  float e = __builtin_amdgcn_exp2f(z2);
  float r = __builtin_amdgcn_rcpf(1.0f + e);
  return v - v * r;
}

// async global->LDS, 16B per lane. LDS dest is wave-uniform base + lane*16;
// global address is per-lane (exploited for the XOR bank swizzle).
__device__ __forceinline__ void g2l16(const void* g, void* l) {
  __builtin_amdgcn_global_load_lds(
      (const __attribute__((address_space(1))) unsigned*)g,
      (__attribute__((address_space(3))) unsigned*)l, 16, 0, 0);
}

// exclusive prefix of 8 counts, computed per-block
__device__ __forceinline__ int prefix_base(const int* counts, int e) {
  int b = 0;
#pragma unroll
  for (int j = 0; j < NE; j++) b += (j < e) ? counts[j] : 0;
  return b;
}

// ---------------- Prep: router; each block also converts a fixed
// 2048-float4 slice of w1 (f32->bf16). R3-R6 accounting: dedicated cvt
// passes cost ~130us serial; micro-slices ride the same blocks' BW while
// the router is VALU-bound. 2048 blocks x 2048 f4 = exactly w1 (4,194,304).
__global__ __launch_bounds__(256) void prep_kernel(
    const float* __restrict__ x, const float* __restrict__ rw,
    const float* __restrict__ w1,
    u16* __restrict__ xb, u16* __restrict__ w1b,
    int* __restrict__ tope, float2* __restrict__ gate2,
    int* __restrict__ counts) {
  int blk = blockIdx.x;
  if (blk == 0 && threadIdx.x < NE) counts[threadIdx.x] = 0;

  // ---- w1 cvt slice: 8 float4 per thread, coalesced
  {
    const float4* s4 = (const float4*)w1;
    int b0 = blk * 2048 + threadIdx.x;
#pragma unroll
    for (int k = 0; k < 8; ++k) {
      int i = b0 + k * 256;
      float4 v = s4[i];
      *(ushort4*)(w1b + (size_t)i * 4) = make_ushort4(
          f32_to_bf16(v.x), f32_to_bf16(v.y), f32_to_bf16(v.z), f32_to_bf16(v.w));
    }
  }

  // ---- router: one wave per token, fp64 logits (exact ranking vs ref)
  int wave = threadIdx.x >> 6;
  int lane = threadIdx.x & 63;
  int t = blk * 4 + wave;
  const float4* x4 = (const float4*)(x + (size_t)t * H_DIM);
  const float4* rw4 = (const float4*)rw;
  u16* xbrow = xb + (size_t)t * H_DIM;

  double acc[NE];
#pragma unroll
  for (int e = 0; e < NE; e++) acc[e] = 0.0;
#pragma unroll
  for (int i = 0; i < 4; i++) {
    int c = lane + 64 * i;
    float4 xv = x4[c];
    ushort4 bv = make_ushort4(f32_to_bf16(xv.x), f32_to_bf16(xv.y),
                              f32_to_bf16(xv.z), f32_to_bf16(xv.w));
    *(ushort4*)(xbrow + c * 4) = bv;
#pragma unroll
    for (int e = 0; e < NE; e++) {
      float4 wv = rw4[e * 256 + c];
      acc[e] += (double)xv.x * wv.x + (double)xv.y * wv.y +
                (double)xv.z * wv.z + (double)xv.w * wv.w;
    }
  }
#pragma unroll
  for (int off = 32; off >= 1; off >>= 1)
#pragma unroll
    for (int e = 0; e < NE; e++) acc[e] += __shfl_xor(acc[e], off, 64);

  if (lane == 0) {
    int e0 = 0; double v0 = acc[0];
#pragma unroll
    for (int e = 1; e < NE; e++) if (acc[e] > v0) { v0 = acc[e]; e0 = e; }
    int e1 = -1; double v1 = -1e300;
#pragma unroll
    for (int e = 0; e < NE; e++) if (e != e0 && acc[e] > v1) { v1 = acc[e]; e1 = e; }
    double ex = exp(v1 - v0);
    tope[t] = e0 | (e1 << 8);
    gate2[t] = make_float2((float)(1.0 / (1.0 + ex)), (float)(ex / (1.0 + ex)));
  }
}

// ---------------- Build expert lists: counting sort over 8 bins.
__global__ __launch_bounds__(256) void build_kernel(
    const int* __restrict__ tope, int* __restrict__ counts,
    int* __restrict__ tok_list, int2* __restrict__ pos2) {
  __shared__ int cts[4][NE];
  __shared__ int gbase[NE];
  int tid = threadIdx.x, lane = tid & 63, w = tid >> 6;
  int t = blockIdx.x * 256 + tid;
  int pk = tope[t];
  int e0 = pk & 0xff, e1 = (pk >> 8) & 0xff;
  unsigned long long lt = ((unsigned long long)1 << lane) - 1;

  int r0 = 0, r1 = 0;
#pragma unroll
  for (int e = 0; e < NE; e++) {
    unsigned long long b0 = __ballot(e0 == e);
    unsigned long long b1 = __ballot(e1 == e);
    int n0 = __popcll(b0), n1 = __popcll(b1);
    if (e0 == e) r0 = __popcll(b0 & lt);
    if (e1 == e) r1 = n0 + __popcll(b1 & lt);
    if (lane == 0) cts[w][e] = n0 + n1;
  }
  __syncthreads();
  if (tid < NE) {
    int bt = cts[0][tid] + cts[1][tid] + cts[2][tid] + cts[3][tid];
    gbase[tid] = atomicAdd(&counts[tid], bt);
  }
  __syncthreads();
  int off0 = gbase[e0] + r0;
  int off1 = gbase[e1] + r1;
#pragma unroll
  for (int wp = 0; wp < 4; wp++) {
    if (wp < w) { off0 += cts[wp][e0]; off1 += cts[wp][e1]; }
  }
  tok_list[e0 * T_TOK + off0] = t;
  tok_list[e1 * T_TOK + off1] = t;
  pos2[t] = make_int2(off0, off1);
}

// ---------------- Grouped GEMM: R3's proven minimum-sync double-buffer
// schedule (256x256 tile, BK=64, 8 waves 2Mx4N, LDS 128 KiB, measured
// 0 bank conflicts, ~101us each). NEW: CVTW2 template arg -- every block
// (active AND early-exit; Sum(cnt)=16384 -> <=576 active of 2048, so
// >=1472 empties guaranteed) converts a fixed 2048-float4 slice of w2
// before its GEMM work. Complete deterministic coverage: 2048 blocks x
// 2048 f4 = w2 exactly. Costs active blocks ~1-2us; rides otherwise-idle
// BW (g1 is MFMA/sync-bound at 24% HBM).
//
// Per K-tile t (buf d = t&1), exactly ONE barrier + ONE vmcnt:
//   vmcnt(0); s_barrier; stage(t+1)->buf d^1 (8 g2l16, WAR-safe);
//   24 ds_read_b128 of buf d; setprio(1); 64 MFMA; setprio(0)
// XOR swizzle: phys 16B-chunk = logical ^ (row&7), staged via pre-swizzled
// GLOBAL source + linear LDS dest. XCD pinning: e = blockIdx&7 (bijective,
// gemm grid %8==0; FETCH 164->57MB proven in R3).
template <int NKT, int NT, int OUTN, bool GATHER, bool GELU, bool CVTW2>
__global__ __launch_bounds__(512, 1) void moe_gemm(
    const u16* __restrict__ A, const u16* __restrict__ W,
    u16* __restrict__ O, const int* __restrict__ tok_list,
    const int* __restrict__ counts,
    const float* __restrict__ cvt_src, u16* __restrict__ cvt_dst) {
  if (CVTW2) {
    // w2 cvt slice: 4 float4 per thread (512 thr), coalesced, idempotent
    const float4* s4 = (const float4*)cvt_src;
    int b0 = blockIdx.x * 2048 + threadIdx.x;
#pragma unroll
    for (int k = 0; k < 4; ++k) {
      int i = b0 + k * 512;
      float4 v = s4[i];
      *(ushort4*)(cvt_dst + (size_t)i * 4) = make_ushort4(
          f32_to_bf16(v.x), f32_to_bf16(v.y), f32_to_bf16(v.z), f32_to_bf16(v.w));
    }
  }
  int e = blockIdx.x & 7;
  int rem = blockIdx.x >> 3;               // 0 .. 32*NT-1
  int mt = rem / NT, nt = rem % NT;
  int cnt = counts[e];
  int m0 = mt * 256;
  if (m0 >= cnt) return;
  int base = prefix_base(counts, e);
  const int K = NKT * 64;

  __shared__ u16 lA[2][16384];   // [dbuf][256][64] bf16 = 64 KB
  __shared__ u16 lB[2][16384];   // 64 KB

  int tid = threadIdx.x;
  int ln = tid & 63, w = tid >> 6;
  int wr = w >> 2, wc = w & 3;             // 2M x 4N wave grid
  int quad = ln >> 4, l16 = ln & 15;

  // ---- staging: call c covers rows c*64..c*64+63; 16B unit u = c*512+tid;
  // phys slot u&7 holds global chunk (u&7)^(row&7).
  const u16* We = W + (size_t)e * OUTN * K;
  const u16* aptr[4]; const u16* bptr[4];
#pragma unroll
  for (int c = 0; c < 4; ++c) {
    int u = c * 512 + tid;
    int row = u >> 3;
    int chunk = (u & 7) ^ (row & 7);
    int ar = m0 + row; if (ar > cnt - 1) ar = cnt - 1;
    const u16* ab;
    if (GATHER) ab = A + (size_t)tok_list[e * T_TOK + ar] * K;
    else        ab = A + (size_t)(base + ar) * K;
    aptr[c] = ab + chunk * 8;
    bptr[c] = We + (size_t)(nt * 256 + row) * K + chunk * 8;
  }

  // ---- read addresses (u16 within one 16384-u16 buffer)
  int adA[8][2], adB[4][2];
#pragma unroll
  for (int f = 0; f < 8; ++f) {
    int r = wr * 128 + f * 16 + l16;
#pragma unroll
    for (int kk = 0; kk < 2; ++kk)
      adA[f][kk] = r * 64 + ((((kk << 2) | quad) ^ (r & 7)) << 3);
  }
#pragma unroll
  for (int j = 0; j < 4; ++j) {
    int r = wc * 64 + j * 16 + l16;
#pragma unroll
    for (int kk = 0; kk < 2; ++kk)
      adB[j][kk] = r * 64 + ((((kk << 2) | quad) ^ (r & 7)) << 3);
  }

  f32x4 acc[8][4];
#pragma unroll
  for (int i = 0; i < 8; i++)
#pragma unroll
    for (int j = 0; j < 4; j++)
#pragma unroll
      for (int r = 0; r < 4; r++) acc[i][j][r] = 0.f;

  // prologue: tile 0 in flight
#pragma unroll
  for (int c = 0; c < 4; ++c) {
    g2l16(aptr[c], &lA[0][(c * 512 + tid) * 8]);
    g2l16(bptr[c], &lB[0][(c * 512 + tid) * 8]);
  }

#pragma unroll 1
  for (int t = 0; t < NKT; ++t) {
    int d = t & 1;
    asm volatile("s_waitcnt vmcnt(0)" ::: "memory");
    __builtin_amdgcn_s_barrier();
    __builtin_amdgcn_sched_barrier(0);

    const u16* Ab = &lA[d][0];
    const u16* Bb = &lB[d][0];
    // reads in consumption order: af[0], all B, af[1..7]
    bf16x8 af[8], af2[8], bf[4], bf2v[4];
    af[0]  = *(const bf16x8*)(Ab + adA[0][0]);
    af2[0] = *(const bf16x8*)(Ab + adA[0][1]);
#pragma unroll
    for (int j = 0; j < 4; ++j) {
      bf[j]   = *(const bf16x8*)(Bb + adB[j][0]);
      bf2v[j] = *(const bf16x8*)(Bb + adB[j][1]);
    }
#pragma unroll
    for (int f = 1; f < 8; ++f) {
      af[f]  = *(const bf16x8*)(Ab + adA[f][0]);
      af2[f] = *(const bf16x8*)(Ab + adA[f][1]);
    }

    if (t + 1 < NKT) {
#pragma unroll
      for (int c = 0; c < 4; ++c) {
        g2l16(aptr[c] + (t + 1) * 64, &lA[d ^ 1][(c * 512 + tid) * 8]);
        g2l16(bptr[c] + (t + 1) * 64, &lB[d ^ 1][(c * 512 + tid) * 8]);
      }
    }
    __builtin_amdgcn_sched_barrier(0);

    __builtin_amdgcn_s_setprio(1);
#pragma unroll
    for (int mi = 0; mi < 8; ++mi) {
#pragma unroll
      for (int ni = 0; ni < 4; ++ni)
        acc[mi][ni] = __builtin_amdgcn_mfma_f32_16x16x32_bf16(
            af[mi], bf[ni], acc[mi][ni], 0, 0, 0);
#pragma unroll
      for (int ni = 0; ni < 4; ++ni)
        acc[mi][ni] = __builtin_amdgcn_mfma_f32_16x16x32_bf16(
            af2[mi], bf2v[ni], acc[mi][ni], 0, 0, 0);
    }
    __builtin_amdgcn_s_setprio(0);
  }

  // epilogue: C/D layout col=lane&15, row=quad*4+reg
#pragma unroll
  for (int mi = 0; mi < 8; ++mi) {
    int rb = wr * 128 + mi * 16 + quad * 4;
#pragma unroll
    for (int r = 0; r < 4; ++r) {
      int grow = m0 + rb + r;
      if (grow < cnt) {
        size_t o = (size_t)(base + grow) * OUTN + nt * 256 + wc * 64 + l16;
#pragma unroll
        for (int ni = 0; ni < 4; ++ni) {
          float v = acc[mi][ni][r];
          if (GELU) v = fast_gelu(v);
          O[o + ni * 16] = f32_to_bf16(v);
        }
      }
    }
  }
}

// ---------------- Combine: out[t] = g0*y[slot0(t)] + g1*y[slot1(t)]
__global__ __launch_bounds__(256) void combine_kernel(
    const u16* __restrict__ y, const int* __restrict__ tope,
    const float2* __restrict__ gate2, const int2* __restrict__ pos2,
    const int* __restrict__ counts, float* __restrict__ out) {
  int t = blockIdx.x;
  int pk = tope[t];
  int e0 = pk & 0xff, e1 = (pk >> 8) & 0xff;
  float2 g = gate2[t];
  int2 p = pos2[t];
  int hb0 = prefix_base(counts, e0);
  int hb1 = prefix_base(counts, e1);
  size_t s0 = (size_t)(hb0 + p.x) * H_DIM + threadIdx.x * 4;
  size_t s1 = (size_t)(hb1 + p.y) * H_DIM + threadIdx.x * 4;
  ushort4 a = *(const ushort4*)(y + s0);
  ushort4 b = *(const ushort4*)(y + s1);
  float4 o;
  o.x = g.x * bf2f(a.x) + g.y * bf2f(b.x);
  o.y = g.x * bf2f(a.y) + g.y * bf2f(b.y);
  o.z = g.x * bf2f(a.z) + g.y * bf2f(b.z);
  o.w = g.x * bf2f(a.w) + g.y * bf2f(b.w);
  *(float4*)(out + (size_t)t * H_DIM + threadIdx.x * 4) = o;
}

extern "C" void kernel_launch(void* const* d_in, const int* in_sizes, int n_in,
                              void* d_out, int out_size, void* d_ws, size_t ws_size,
                              hipStream_t stream) {
  const float* x  = (const float*)d_in[0];
  const float* rw = (const float*)d_in[1];
  const float* w1 = (const float*)d_in[2];
  const float* w2 = (const float*)d_in[3];
  float* out = (float*)d_out;

  // ws layout (bytes), total ~151.5 MB. y aliases w1b (dead after g1).
  char* ws = (char*)d_ws;
  u16* xb       = (u16*)(ws);                        // 16,777,216
  u16* w1b      = (u16*)(ws + 16777216);             // 33,554,432
  u16* y        = (u16*)(ws + 16777216);             // alias of w1b
  u16* w2b      = (u16*)(ws + 50331648);             // 33,554,432
  u16* h        = (u16*)(ws + 83886080);             // 67,108,864
  int* tok_list = (int*)(ws + 150994944);            // 262,144
  int* tope     = (int*)(ws + 151257088);            // 32,768
  float2* gate2 = (float2*)(ws + 151289856);         // 65,536
  int2* pos2    = (int2*)(ws + 151355392);           // 65,536
  int* counts   = (int*)(ws + 151420928);            // 32

  // prep: router, each block also converts a 2048-f4 slice of w1
  prep_kernel<<<T_TOK / 4, 256, 0, stream>>>(x, rw, w1, xb, w1b,
                                             tope, gate2, counts);
  build_kernel<<<T_TOK / 256, 256, 0, stream>>>(tope, counts, tok_list, pos2);
  // g1: gathered [cnt_e,1024](bf16) @ w1[e]^T -> gelu -> h [.,2048]
  //     every block also converts a 2048-f4 slice of w2 (complete coverage)
  moe_gemm<16, 8, H2, true, true, true>
      <<<NE * 32 * 8, 512, 0, stream>>>(xb, w1b, h, tok_list, counts, w2, w2b);
  // g2: h [cnt_e,2048] @ w2[e]^T -> y [.,1024]
  moe_gemm<32, 4, H_DIM, false, false, false>
      <<<NE * 32 * 4, 512, 0, stream>>>(h, w2b, y, tok_list, counts,
                                        nullptr, nullptr);
  combine_kernel<<<T_TOK, 256, 0, stream>>>(y, tope, gate2, pos2, counts, out);
}